// Round 1
// baseline (165.894 us; speedup 1.0000x reference)
//
#include <hip/hip_runtime.h>

typedef short s16x8 __attribute__((ext_vector_type(8)));
typedef float f32x4 __attribute__((ext_vector_type(4)));
typedef float f32x16 __attribute__((ext_vector_type(16)));

#define B_ 4
#define C_ 256
#define S_ 4096
#define LOG2E 1.44269504088896f
#define M2 32.0f   // fixed base-2 softmax offset: p = 2^(s' - M2)

#if __has_builtin(__builtin_amdgcn_exp2f)
#define EXP2(x) __builtin_amdgcn_exp2f(x)
#else
#define EXP2(x) __exp2f(x)
#endif

// RNE float -> bf16
__device__ __forceinline__ unsigned short f2b(float f) {
  union { float f; unsigned u; } v; v.f = f;
  unsigned r = v.u + 0x7fffu + ((v.u >> 16) & 1u);
  return (unsigned short)(r >> 16);
}
// cheap round-half-up float -> bf16 (hot loop)
__device__ __forceinline__ unsigned short f2b_fast(float f) {
  union { float f; unsigned u; } v; v.f = f;
  return (unsigned short)((v.u + 0x8000u) >> 16);
}
// 16B LDS load at 8B alignment (rows strided by 68 shorts = 136B)
__device__ __forceinline__ s16x8 lds_ld8(const unsigned short* p) {
  union { s16x8 v; uint2 u[2]; } r;
  r.u[0] = *(const uint2*)p;
  r.u[1] = *(const uint2*)(p + 4);
  return r.v;
}

// ---- fused QKV projection (MFMA) --------------------------------------------
// ct==0:  rows 0-31 = Q (scaled by LOG2E), rows 32-63 = K (from input)
// ct 1-4: rows = Wv[(ct-1)*64 .. +64) (from original)
// Qb,Kb: [B][S][32] bf16 (n-major).
// Vf: fragment-order tiles: [b][jt][cg][vv][kb][lane64][8] bf16 (8 MB), where
//     element = V[ch = cg*64+vv*32+(lane&31)][j = jt*64 + kb*16 + (lane>>5)*8 + e]
__global__ __launch_bounds__(256)
void proj_kernel(const float* __restrict__ x, const float* __restrict__ orig,
                 const float* __restrict__ wq, const float* __restrict__ bq,
                 const float* __restrict__ wk, const float* __restrict__ bk,
                 const float* __restrict__ wv, const float* __restrict__ bv,
                 unsigned short* __restrict__ Qb, unsigned short* __restrict__ Kb,
                 unsigned short* __restrict__ Vf) {
  __shared__ unsigned short Al[64 * 68];
  __shared__ unsigned short Sl[64 * 68];
  const int ct = blockIdx.x >> 6;
  const int jt = blockIdx.x & 63;
  const int n0 = jt * 64;
  const int b  = blockIdx.y;
  const int t  = threadIdx.x;
  const int L = t & 63, w = t >> 6;
  const int mt = w >> 1, nt = w & 1;
  const int g = L >> 5, l32 = L & 31;
  const float* srcb = ((ct == 0) ? x : orig) + (size_t)b * C_ * S_;
  f32x16 acc = (f32x16)0.0f;

  for (int kc = 0; kc < 4; ++kc) {
    const int k0 = kc * 64;
    __syncthreads();
    // stage weights Al[row][c] (64x64)
    #pragma unroll
    for (int rep = 0; rep < 4; ++rep) {
      const int idx = rep * 256 + t;
      const int row = idx >> 4, c4 = (idx & 15) * 4;
      const float* wsrc; int wrow;
      if (ct == 0) {
        if (row < 32) { wsrc = wq; wrow = row; } else { wsrc = wk; wrow = row - 32; }
      } else { wsrc = wv; wrow = (ct - 1) * 64 + row; }
      f32x4 v = *(const f32x4*)(wsrc + (size_t)wrow * 256 + k0 + c4);
      union { unsigned short us[4]; uint2 u2; } pk;
      #pragma unroll
      for (int i = 0; i < 4; ++i) pk.us[i] = f2b(v[i]);
      *(uint2*)&Al[row * 68 + c4] = pk.u2;
    }
    // stage source transposed Sl[n][c], vectorized 8B LDS writes
    {
      const int c4 = (t >> 4) * 4;
      const int n4 = (t & 15) * 4;
      f32x4 v0 = *(const f32x4*)(srcb + (size_t)(k0 + c4 + 0) * S_ + n0 + n4);
      f32x4 v1 = *(const f32x4*)(srcb + (size_t)(k0 + c4 + 1) * S_ + n0 + n4);
      f32x4 v2 = *(const f32x4*)(srcb + (size_t)(k0 + c4 + 2) * S_ + n0 + n4);
      f32x4 v3 = *(const f32x4*)(srcb + (size_t)(k0 + c4 + 3) * S_ + n0 + n4);
      #pragma unroll
      for (int k = 0; k < 4; ++k) {
        union { unsigned short us[4]; uint2 u2; } pk;
        pk.us[0] = f2b(v0[k]); pk.us[1] = f2b(v1[k]);
        pk.us[2] = f2b(v2[k]); pk.us[3] = f2b(v3[k]);
        *(uint2*)&Sl[(n4 + k) * 68 + c4] = pk.u2;
      }
    }
    __syncthreads();
    #pragma unroll
    for (int ks = 0; ks < 4; ++ks) {
      s16x8 af = lds_ld8(&Al[(mt * 32 + l32) * 68 + ks * 16 + g * 8]);
      s16x8 bf = lds_ld8(&Sl[(nt * 32 + l32) * 68 + ks * 16 + g * 8]);
      acc = __builtin_amdgcn_mfma_f32_32x32x16_bf16(af, bf, acc, 0, 0, 0);
    }
  }
  __syncthreads();   // LDS free; reuse Al as repack buffer
  unsigned short* Rl = Al;
  const int n = nt * 32 + l32;
  if (ct == 0) {
    // dump [n][ch]: ch 0..31 = Q, 32..63 = K
    #pragma unroll
    for (int reg = 0; reg < 16; ++reg) {
      const int rr = (reg & 3) + 8 * (reg >> 2) + 4 * g;
      const float val = (mt == 0) ? (acc[reg] + bq[rr]) * LOG2E : acc[reg] + bk[rr];
      Rl[n * 68 + mt * 32 + rr] = f2b(val);
    }
    __syncthreads();
    const int nn = t >> 2, ch0 = (t & 3) * 16;
    s16x8 a = lds_ld8(Rl + nn * 68 + ch0);
    s16x8 c = lds_ld8(Rl + nn * 68 + ch0 + 8);
    unsigned short* dst = (ch0 < 32)
        ? Qb + ((size_t)b * S_ + n0 + nn) * 32 + ch0
        : Kb + ((size_t)b * S_ + n0 + nn) * 32 + (ch0 - 32);
    *(s16x8*)dst = a;
    *(s16x8*)(dst + 8) = c;
  } else {
    const int cg = ct - 1;
    // dump [ch][j]
    #pragma unroll
    for (int reg = 0; reg < 16; ++reg) {
      const int rr = (reg & 3) + 8 * (reg >> 2) + 4 * g;
      const int ch = mt * 32 + rr;
      Rl[ch * 68 + n] = f2b(acc[reg] + bv[cg * 64 + ch]);
    }
    __syncthreads();
    unsigned short* grp = Vf + ((size_t)(b * 64 + jt) * 4 + cg) * 4096;
    #pragma unroll
    for (int k = 0; k < 2; ++k) {
      const int G = t * 2 + k;
      const int vv = G >> 8, kb = (G >> 6) & 3, Lf = G & 63;
      const int ch64 = vv * 32 + (Lf & 31);
      const int j64  = kb * 16 + (Lf >> 5) * 8;
      s16x8 v = lds_ld8(Rl + ch64 * 68 + j64);
      *(s16x8*)(grp + G * 8) = v;
    }
  }
}

// ---- flash attention, fixed-offset base-2 softmax ---------------------------
// 512 threads (8 waves), i-tile 64, grid 256 (2 blocks/CU), j-tile 64.
// Phase A: wave (rh,jh): rows rh*16.. x j-half jh*32..; p = exp2(s-M2); P->LDS.
// Phase B: wave (dup,cg): 64 ch (cg) x 64 i, kb-split (dup) -> 4 accs;
//          V fragments via single coalesced global loads (pre-swizzled Vf).
union FlashU {
  unsigned short P[64 * 68];   // 8704 B
  float scr[2][32 * 258];      // 66048 B (epilogue, 2 dup planes x 32 i-rows)
};

__global__ __launch_bounds__(512, 4)
void flash_kernel(const unsigned short* __restrict__ Qb,
                  const unsigned short* __restrict__ Kb,
                  const unsigned short* __restrict__ Vf,
                  const float* __restrict__ inp,
                  const float* __restrict__ gamma,
                  float* __restrict__ out) {
  __shared__ FlashU sm;
  __shared__ float lpart[2][64];
  __shared__ float invl[64];
  const int l  = blockIdx.x;
  const int b  = (l & 7) >> 1;                       // XCD pair per batch
  const int i0 = ((l >> 3) * 2 + (l & 1)) * 64;
  const int t  = threadIdx.x;
  const int L = t & 63, w = t >> 6;
  const int q4 = L >> 4, c16 = L & 15;
  const int g  = L >> 5, l32 = L & 31;
  const int rh = w & 3, jh = w >> 2;                 // phase A role
  const int cg = w & 3, dup = w >> 2;                // phase B role
  const float gam = gamma[0];
  const unsigned short* Kbase = Kb + (size_t)b * S_ * 32;
  const s16x8 qf = *(const s16x8*)(Qb + ((size_t)b * S_ + i0 + rh * 16 + c16) * 32 + q4 * 8);

  f32x16 acc00 = (f32x16)0.0f, acc01 = (f32x16)0.0f;  // i 0..31  x ch {vv0,vv1}
  f32x16 acc10 = (f32x16)0.0f, acc11 = (f32x16)0.0f;  // i 32..63
  float lp[4] = {0.f, 0.f, 0.f, 0.f};

  // preload K frags for j0=0
  s16x8 kc0 = *(const s16x8*)(Kbase + (size_t)(jh * 32 + c16) * 32 + q4 * 8);
  s16x8 kc1 = *(const s16x8*)(Kbase + (size_t)(jh * 32 + 16 + c16) * 32 + q4 * 8);

  for (int j0 = 0; j0 < S_; j0 += 64) {
    const int jt = j0 >> 6;
    // prefetch next-iter K frags (consumed next phase A)
    const int jn = (j0 + 64 < S_) ? j0 + 64 : j0;
    s16x8 kn0 = *(const s16x8*)(Kbase + (size_t)(jn + jh * 32 + c16) * 32 + q4 * 8);
    s16x8 kn1 = *(const s16x8*)(Kbase + (size_t)(jn + jh * 32 + 16 + c16) * 32 + q4 * 8);
    // V fragments: one coalesced 1KB load each (pre-swizzled layout)
    const unsigned short* vbase = Vf + ((size_t)(b * 64 + jt) * 4 + cg) * 4096;
    s16x8 vf00 = *(const s16x8*)(vbase + (dup * 2 + 0) * 512 + L * 8);           // vv=0,kk=0
    s16x8 vf01 = *(const s16x8*)(vbase + 2048 + (dup * 2 + 0) * 512 + L * 8);    // vv=1,kk=0
    s16x8 vf10 = *(const s16x8*)(vbase + (dup * 2 + 1) * 512 + L * 8);           // vv=0,kk=1
    s16x8 vf11 = *(const s16x8*)(vbase + 2048 + (dup * 2 + 1) * 512 + L * 8);    // vv=1,kk=1
    // ---- Phase A
    f32x4 cinit = (f32x4)(-M2);
    f32x4 s0 = __builtin_amdgcn_mfma_f32_16x16x32_bf16(qf, kc0, cinit, 0, 0, 0);
    f32x4 s1 = __builtin_amdgcn_mfma_f32_16x16x32_bf16(qf, kc1, cinit, 0, 0, 0);
    #pragma unroll
    for (int r = 0; r < 4; ++r) {
      const float p0 = EXP2(s0[r]);
      const float p1 = EXP2(s1[r]);
      lp[r] += p0 + p1;
      const int row = rh * 16 + q4 * 4 + r;
      sm.P[row * 68 + jh * 32 + c16]      = f2b_fast(p0);
      sm.P[row * 68 + jh * 32 + 16 + c16] = f2b_fast(p1);
    }
    __syncthreads();   // P visible (also drains vf, needed immediately)
    // ---- Phase B: kb-split (dup), 2x2 register blocking
    {
      const int ko0 = (dup * 2 + 0) * 16 + g * 8;
      const s16x8 pf0 = lds_ld8(sm.P + l32 * 68 + ko0);
      const s16x8 pf1 = lds_ld8(sm.P + (32 + l32) * 68 + ko0);
      acc00 = __builtin_amdgcn_mfma_f32_32x32x16_bf16(pf0, vf00, acc00, 0, 0, 0);
      acc01 = __builtin_amdgcn_mfma_f32_32x32x16_bf16(pf0, vf01, acc01, 0, 0, 0);
      acc10 = __builtin_amdgcn_mfma_f32_32x32x16_bf16(pf1, vf00, acc10, 0, 0, 0);
      acc11 = __builtin_amdgcn_mfma_f32_32x32x16_bf16(pf1, vf01, acc11, 0, 0, 0);
    }
    {
      const int ko1 = (dup * 2 + 1) * 16 + g * 8;
      const s16x8 pf0 = lds_ld8(sm.P + l32 * 68 + ko1);
      const s16x8 pf1 = lds_ld8(sm.P + (32 + l32) * 68 + ko1);
      acc00 = __builtin_amdgcn_mfma_f32_32x32x16_bf16(pf0, vf10, acc00, 0, 0, 0);
      acc01 = __builtin_amdgcn_mfma_f32_32x32x16_bf16(pf0, vf11, acc01, 0, 0, 0);
      acc10 = __builtin_amdgcn_mfma_f32_32x32x16_bf16(pf1, vf10, acc10, 0, 0, 0);
      acc11 = __builtin_amdgcn_mfma_f32_32x32x16_bf16(pf1, vf11, acc11, 0, 0, 0);
    }
    __syncthreads();   // P consumed
    kc0 = kn0; kc1 = kn1;
  }
  // ---- l reduction
  #pragma unroll
  for (int r = 0; r < 4; ++r) {
    float v = lp[r];
    #pragma unroll
    for (int d = 1; d < 16; d <<= 1) v += __shfl_xor(v, d, 64);
    lp[r] = v;
  }
  if (c16 == 0) {
    #pragma unroll
    for (int r = 0; r < 4; ++r) lpart[jh][rh * 16 + q4 * 4 + r] = lp[r];
  }
  __syncthreads();
  if (t < 64) invl[t] = gam / (lpart[0][t] + lpart[1][t]);
  // ---- epilogue: 2 passes over i-halves; dup planes summed at store
  #pragma unroll
  for (int h = 0; h < 2; ++h) {
    const f32x16 a0 = h ? acc10 : acc00;
    const f32x16 a1 = h ? acc11 : acc01;
    float* pl = sm.scr[dup];
    #pragma unroll
    for (int reg = 0; reg < 16; ++reg) {
      const int rr = (reg & 3) + 8 * (reg >> 2) + 4 * g;
      pl[rr * 258 + cg * 64 + l32]      = a0[reg];
      pl[rr * 258 + cg * 64 + 32 + l32] = a1[reg];
    }
    __syncthreads();   // (first pass also publishes invl)
    const int ch = t >> 1;
    const int il16 = (t & 1) * 16;
    #pragma unroll
    for (int q = 0; q < 4; ++q) {
      const int iloc = il16 + q * 4;
      const size_t gi = ((size_t)b * C_ + ch) * S_ + i0 + h * 32 + iloc;
      const f32x4 iv = *(const f32x4*)(inp + gi);
      f32x4 o;
      #pragma unroll
      for (int k = 0; k < 4; ++k) {
        const int il = iloc + k;
        o[k] = (sm.scr[0][il * 258 + ch] + sm.scr[1][il * 258 + ch]) * invl[h * 32 + il] + iv[k];
      }
      *(f32x4*)(out + gi) = o;
    }
    __syncthreads();   // scr free for next pass
  }
}

// ---- launch -----------------------------------------------------------------
extern "C" void kernel_launch(void* const* d_in, const int* in_sizes, int n_in,
                              void* d_out, int out_size, void* d_ws, size_t ws_size,
                              hipStream_t stream) {
  const float* inp   = (const float*)d_in[0];
  const float* orig  = (const float*)d_in[1];
  const float* wq    = (const float*)d_in[2];
  const float* bq    = (const float*)d_in[3];
  const float* wk    = (const float*)d_in[4];
  const float* bk    = (const float*)d_in[5];
  const float* wv    = (const float*)d_in[6];
  const float* bv    = (const float*)d_in[7];
  const float* gamma = (const float*)d_in[8];
  float* out = (float*)d_out;

  unsigned short* Qb = (unsigned short*)d_ws;            // [B][S][32] bf16, 1 MB
  unsigned short* Kb = Qb + (size_t)B_ * S_ * 32;        // [B][S][32] bf16, 1 MB
  unsigned short* Vf = Kb + (size_t)B_ * S_ * 32;        // frag-tiled V, 8 MB

  proj_kernel<<<dim3(320, 4), 256, 0, stream>>>(inp, orig, wq, bq, wk, bk, wv, bv, Qb, Kb, Vf);
  flash_kernel<<<256, 512, 0, stream>>>(Qb, Kb, Vf, inp, gamma, out);
}